// Round 1
// 1691.216 us; speedup vs baseline: 2.2623x; 2.2623x over previous
//
#include <hip/hip_runtime.h>
#include <hip/hip_bf16.h>

typedef unsigned short u16;
typedef short short8 __attribute__((ext_vector_type(8)));
typedef short short4v __attribute__((ext_vector_type(4)));
typedef float f32x4 __attribute__((ext_vector_type(4)));

#define B_SZ 2048
#define T_SZ 32
#define E_SZ 1024
#define H_SZ 16
#define HS_SZ 64
// tokens = B*T = 65536; heads total BH = 32768

// Static device intermediates
__device__ __align__(16) u16 g_Wt[3 * E_SZ * E_SZ];            // stacked [Wq^T;Wk^T;Wv^T]: row j=(which,h,d), col e
__device__ __align__(16) u16 g_Wpt[E_SZ * E_SZ];               // (j,e) = Wp^T bf16
__device__ __align__(16) u16 g_xb[(size_t)B_SZ * T_SZ * E_SZ]; // x bf16 [65536][1024]
__device__ __align__(16) u16 g_Q[(size_t)B_SZ * H_SZ * T_SZ * HS_SZ];  // [bh][t][d]
__device__ __align__(16) u16 g_K[(size_t)B_SZ * H_SZ * T_SZ * HS_SZ];  // [bh][t][d]
__device__ __align__(16) u16 g_Vt[(size_t)B_SZ * H_SZ * HS_SZ * T_SZ]; // [bh][d][t]  (transposed!)
__device__ __align__(16) u16 g_O[(size_t)B_SZ * T_SZ * E_SZ];  // attn out bf16 [65536][1024]

__device__ __forceinline__ f32x4 mfma16x16x32(short8 a, short8 b, f32x4 c) {
    return __builtin_amdgcn_mfma_f32_16x16x32_bf16(a, b, c, 0, 0, 0);
}

__device__ __forceinline__ u16 f2bf(float f) {
    __hip_bfloat16 h = __float2bfloat16(f);
    return __builtin_bit_cast(u16, h);
}

// async global->LDS, 16B per lane. lds ptr must be wave-uniform base; HW adds lane*16.
__device__ __forceinline__ void gll16(const void* g, void* l) {
    __builtin_amdgcn_global_load_lds(
        (__attribute__((address_space(1))) void*)g,
        (__attribute__((address_space(3))) void*)l, 16, 0, 0);
}

__device__ __forceinline__ float rmax16(float v) {
    v = fmaxf(v, __shfl_xor(v, 1));
    v = fmaxf(v, __shfl_xor(v, 2));
    v = fmaxf(v, __shfl_xor(v, 4));
    v = fmaxf(v, __shfl_xor(v, 8));
    return v;
}
__device__ __forceinline__ float rsum16(float v) {
    v += __shfl_xor(v, 1);
    v += __shfl_xor(v, 2);
    v += __shfl_xor(v, 4);
    v += __shfl_xor(v, 8);
    return v;
}

// ---------- fp32 -> bf16 convert of x (coalesced float4 loads) ----------
// grid = B*T*E/2048 = 32768 blocks of 256
__global__ __launch_bounds__(256) void xconv_kernel(const float* __restrict__ x) {
    size_t base = (size_t)blockIdx.x * 2048;
    int t = threadIdx.x;
    #pragma unroll
    for (int hh = 0; hh < 2; hh++) {
        size_t i = base + (size_t)hh * 1024 + (size_t)t * 4;
        float4 v = *(const float4*)(x + i);
        short4v o;
        o[0] = (short)f2bf(v.x); o[1] = (short)f2bf(v.y);
        o[2] = (short)f2bf(v.z); o[3] = (short)f2bf(v.w);
        *(short4v*)(g_xb + i) = o;
    }
}

// ---------- Wq/Wk/Wv (H,E,HS) fp32 -> stacked g_Wt rows (which,h,d) over e ----------
// grid=(3*H, E/64), block=256
__global__ __launch_bounds__(256) void wconv_qkv_kernel(
    const float* __restrict__ Wq, const float* __restrict__ Wk,
    const float* __restrict__ Wv)
{
    __shared__ float tile[64][65];
    int which = blockIdx.x >> 4;
    int h = blockIdx.x & 15;
    int rt = blockIdx.y;   // e-tile
    const float* in = (which == 0 ? Wq : which == 1 ? Wk : Wv) + (size_t)h * E_SZ * HS_SZ;
    u16* out = g_Wt + (size_t)which * E_SZ * E_SZ + (size_t)h * HS_SZ * E_SZ;
    int t = threadIdx.x;
    #pragma unroll
    for (int i = 0; i < 16; i++) {
        int idx = t + i * 256;
        int r = idx >> 6, c = idx & 63;
        tile[r][c] = in[(size_t)(rt * 64 + r) * HS_SZ + c];
    }
    __syncthreads();
    #pragma unroll
    for (int i = 0; i < 16; i++) {
        int idx = t + i * 256;
        int r = idx >> 6, c = idx & 63;
        out[(size_t)r * E_SZ + rt * 64 + c] = f2bf(tile[c][r]);
    }
}

// ---------- Wp (E,E) fp32 -> g_Wpt[j][e] = Wp[e][j] bf16 ----------
__global__ __launch_bounds__(256) void wconv_p_kernel(const float* __restrict__ Wp) {
    __shared__ float tile[64][65];
    int rt = blockIdx.x, ct = blockIdx.y;
    int t = threadIdx.x;
    #pragma unroll
    for (int i = 0; i < 16; i++) {
        int idx = t + i * 256;
        int r = idx >> 6, c = idx & 63;
        tile[r][c] = Wp[(size_t)(rt * 64 + r) * E_SZ + ct * 64 + c];
    }
    __syncthreads();
    #pragma unroll
    for (int i = 0; i < 16; i++) {
        int idx = t + i * 256;
        int r = idx >> 6, c = idx & 63;
        g_Wpt[(size_t)(ct * 64 + r) * E_SZ + rt * 64 + c] = f2bf(tile[c][r]);
    }
}

// ---------- QKV GEMM: C[65536][3072] = g_xb @ g_Wt^T, m97 structure ----------
// 128x128 tile, BK=32, 4 waves (2x2), 16 MFMA / K-step, global_load_lds width 16.
// Epilogue stages C tile in LDS (bf16) and flushes to g_Q/g_K (coalesced) or g_Vt (transposed).
// grid = dim3(512, 24), block 256.
__global__ __launch_bounds__(256) void qkv_gemm_kernel() {
    __shared__ u16 smem[16384];   // K-loop: A=smem[0..4095], B=smem[4096..8191]; epilogue: C[128][128]
    int tid = threadIdx.x;
    int wave = tid >> 6, lane = tid & 63;
    int m = lane & 15, quad = lane >> 4;
    int wr = wave >> 1, wc = wave & 1;
    int bm = blockIdx.x, bn = blockIdx.y;

    const u16* Aglob = g_xb + (size_t)bm * 128 * E_SZ;
    const u16* Bglob = g_Wt + (size_t)bn * 128 * E_SZ;

    f32x4 acc[4][4] = {};

    for (int k0 = 0; k0 < E_SZ; k0 += 32) {
        __syncthreads();   // previous iteration's ds_reads complete
        #pragma unroll
        for (int i = 0; i < 2; i++) {
            int c = wave * 128 + i * 64 + lane;   // 16B chunk index 0..511
            int row = c >> 2, col = (c & 3) * 8;
            gll16(Aglob + (size_t)row * E_SZ + k0 + col,
                  (char*)smem + wave * 2048 + i * 1024);
            gll16(Bglob + (size_t)row * E_SZ + k0 + col,
                  (char*)smem + 8192 + wave * 2048 + i * 1024);
        }
        __syncthreads();   // staging complete (compiler drains vmcnt before barrier)

        short8 af[4], bf[4];
        #pragma unroll
        for (int mi = 0; mi < 4; mi++)
            af[mi] = *(const short8*)&smem[(wr * 64 + mi * 16 + m) * 32 + quad * 8];
        #pragma unroll
        for (int ni = 0; ni < 4; ni++)
            bf[ni] = *(const short8*)&smem[4096 + (wc * 64 + ni * 16 + m) * 32 + quad * 8];
        #pragma unroll
        for (int mi = 0; mi < 4; mi++)
            #pragma unroll
            for (int ni = 0; ni < 4; ni++)
                acc[mi][ni] = mfma16x16x32(af[mi], bf[ni], acc[mi][ni]);
    }
    __syncthreads();   // everyone done with A/B tiles before C reuse

    // acc -> LDS as bf16 C[128][128]
    #pragma unroll
    for (int mi = 0; mi < 4; mi++)
        #pragma unroll
        for (int ni = 0; ni < 4; ni++) {
            int row = wr * 64 + mi * 16 + quad * 4;
            int col = wc * 64 + ni * 16 + m;
            #pragma unroll
            for (int r = 0; r < 4; r++)
                smem[(row + r) * 128 + col] = f2bf(acc[mi][ni][r]);
        }
    __syncthreads();

    int which = bn >> 3;   // 8 col-tiles per matrix
    if (which < 2) {
        // Q/K flush: [bh][t][d], 16B chunks, 128B-contiguous groups
        u16* dst = (which == 0) ? g_Q : g_K;
        #pragma unroll
        for (int i = 0; i < 8; i++) {
            int c = i * 256 + tid;          // 0..2047
            int row = c >> 4;               // token-local 0..127
            int jloc = (c & 15) * 8;
            int jg = bn * 128 + jloc;
            int h = (jg >> 6) & 15;
            int d0 = jg & 63;
            int rg = bm * 128 + row;
            int b = rg >> 5, t = rg & 31;
            size_t off = (((size_t)(b * 16 + h)) * 32 + t) * 64 + d0;
            *(short8*)(dst + off) = *(const short8*)&smem[row * 128 + jloc];
        }
    } else {
        // V flush transposed: g_Vt[bh][d][t]; stores fully coalesced
        #pragma unroll
        for (int i = 0; i < 8; i++) {
            int c = i * 256 + tid;
            int t8 = (c & 3) * 8;           // t chunk base
            int d  = (c >> 2) & 63;
            int hl = (c >> 8) & 1;
            int bl = c >> 9;                // 0..3
            short8 v;
            #pragma unroll
            for (int k = 0; k < 8; k++)
                v[k] = (short)smem[(bl * 32 + t8 + k) * 128 + hl * 64 + d];
            int h = ((bn * 128 + hl * 64) >> 6) & 15;
            int b = bm * 4 + bl;
            size_t off = (((size_t)(b * 16 + h)) * 64 + d) * 32 + t8;
            *(short8*)(g_Vt + off) = v;
        }
    }
}

// ---------- Attention: one WAVE per (b,h); barrier-light; wave-parallel softmax ----------
// grid = 32768/4 = 8192 blocks of 256
__global__ __launch_bounds__(256) void attn_kernel() {
    __shared__ u16 Ps[4][32][40];   // per-wave P (bf16), padded
    int tid = threadIdx.x;
    int wave = tid >> 6, lane = tid & 63;
    int m = lane & 15, quad = lane >> 4;
    int bh = blockIdx.x * 4 + wave;
    int b = bh >> 4, h = bh & 15;

    const u16* Qb = g_Q  + (size_t)bh * 2048;   // [32][64]
    const u16* Kb = g_K  + (size_t)bh * 2048;   // [32][64]
    const u16* Vb = g_Vt + (size_t)bh * 2048;   // [64][32] (V^T)

    // fragment loads (all independent -> issued up front)
    short8 qf[2][2], kf[2][2], vf[4];
    #pragma unroll
    for (int tr = 0; tr < 2; tr++)
        #pragma unroll
        for (int kc = 0; kc < 2; kc++) {
            qf[tr][kc] = *(const short8*)(Qb + (tr * 16 + m) * 64 + kc * 32 + quad * 8);
            kf[tr][kc] = *(const short8*)(Kb + (tr * 16 + m) * 64 + kc * 32 + quad * 8);
        }
    #pragma unroll
    for (int nc = 0; nc < 4; nc++)
        vf[nc] = *(const short8*)(Vb + (nc * 16 + m) * 32 + quad * 8);

    // S = Q K^T (32x32). Tile (0,1) fully causal-masked -> 3 tiles, 6 MFMAs.
    f32x4 s00 = {}, s10 = {}, s11 = {};
    #pragma unroll
    for (int kc = 0; kc < 2; kc++) {
        s00 = mfma16x16x32(qf[0][kc], kf[0][kc], s00);
        s10 = mfma16x16x32(qf[1][kc], kf[0][kc], s10);
        s11 = mfma16x16x32(qf[1][kc], kf[1][kc], s11);
    }

    // wave-parallel causal softmax. Row t lives in the 16 lanes of one quad group.
    #pragma unroll
    for (int r = 0; r < 4; r++) {
        int t0 = quad * 4 + r;
        bool ok = (m <= t0);               // mask for tiles (0,0) and (1,1)
        float x00 = ok ? s00[r] * 0.125f : -1e30f;
        float x10 = s10[r] * 0.125f;       // tile (1,0): always valid
        float x11 = ok ? s11[r] * 0.125f : -1e30f;
        float mx0 = rmax16(x00);
        float mx1 = rmax16(fmaxf(x10, x11));
        float e00 = ok ? __expf(x00 - mx0) : 0.f;
        float e10 = __expf(x10 - mx1);
        float e11 = ok ? __expf(x11 - mx1) : 0.f;
        float inv0 = 1.f / rsum16(e00);
        float inv1 = 1.f / rsum16(e10 + e11);
        Ps[wave][t0][m]           = f2bf(e00 * inv0);
        Ps[wave][t0][16 + m]      = 0;          // masked tile (0,1)
        Ps[wave][16 + t0][m]      = f2bf(e10 * inv1);
        Ps[wave][16 + t0][16 + m] = f2bf(e11 * inv1);
    }
    __syncthreads();

    // O = P (32x32) @ V (32x64): K=32 -> 1 MFMA per 16x16 tile, 8 total.
    short8 pa[2];
    pa[0] = *(const short8*)&Ps[wave][m][quad * 8];
    pa[1] = *(const short8*)&Ps[wave][16 + m][quad * 8];
    f32x4 o[2][4];
    #pragma unroll
    for (int tr = 0; tr < 2; tr++)
        #pragma unroll
        for (int nc = 0; nc < 4; nc++)
            o[tr][nc] = mfma16x16x32(pa[tr], vf[nc], f32x4{});

    u16* ob = g_O + ((size_t)b * 32) * E_SZ + h * 64;
    #pragma unroll
    for (int tr = 0; tr < 2; tr++)
        #pragma unroll
        for (int nc = 0; nc < 4; nc++)
            #pragma unroll
            for (int r = 0; r < 4; r++) {
                int t = tr * 16 + quad * 4 + r;
                ob[(size_t)t * E_SZ + nc * 16 + m] = f2bf(o[tr][nc][r]);
            }
}

// ---------- proj GEMM: out[65536][1024] fp32 = g_O @ Wp + bp, m97 structure ----------
// grid = dim3(512, 8), block 256.
__global__ __launch_bounds__(256) void proj_gemm_kernel(
    float* __restrict__ out, const float* __restrict__ bp)
{
    __shared__ u16 smem[8192];    // A=smem[0..4095], B=smem[4096..8191]
    int tid = threadIdx.x;
    int wave = tid >> 6, lane = tid & 63;
    int m = lane & 15, quad = lane >> 4;
    int wr = wave >> 1, wc = wave & 1;
    int bm = blockIdx.x, bn = blockIdx.y;

    const u16* Aglob = g_O + (size_t)bm * 128 * E_SZ;
    const u16* Bglob = g_Wpt + (size_t)bn * 128 * E_SZ;

    f32x4 acc[4][4] = {};

    for (int k0 = 0; k0 < E_SZ; k0 += 32) {
        __syncthreads();
        #pragma unroll
        for (int i = 0; i < 2; i++) {
            int c = wave * 128 + i * 64 + lane;
            int row = c >> 2, col = (c & 3) * 8;
            gll16(Aglob + (size_t)row * E_SZ + k0 + col,
                  (char*)smem + wave * 2048 + i * 1024);
            gll16(Bglob + (size_t)row * E_SZ + k0 + col,
                  (char*)smem + 8192 + wave * 2048 + i * 1024);
        }
        __syncthreads();

        short8 af[4], bf[4];
        #pragma unroll
        for (int mi = 0; mi < 4; mi++)
            af[mi] = *(const short8*)&smem[(wr * 64 + mi * 16 + m) * 32 + quad * 8];
        #pragma unroll
        for (int ni = 0; ni < 4; ni++)
            bf[ni] = *(const short8*)&smem[4096 + (wc * 64 + ni * 16 + m) * 32 + quad * 8];
        #pragma unroll
        for (int mi = 0; mi < 4; mi++)
            #pragma unroll
            for (int ni = 0; ni < 4; ni++)
                acc[mi][ni] = mfma16x16x32(af[mi], bf[ni], acc[mi][ni]);
    }

    // direct fp32 epilogue + bias
    #pragma unroll
    for (int ni = 0; ni < 4; ni++) {
        int j = bn * 128 + wc * 64 + ni * 16 + m;
        float bias = bp[j];
        #pragma unroll
        for (int mi = 0; mi < 4; mi++) {
            size_t rg = (size_t)bm * 128 + wr * 64 + mi * 16 + quad * 4;
            #pragma unroll
            for (int r = 0; r < 4; r++)
                out[(rg + r) * E_SZ + j] = acc[mi][ni][r] + bias;
        }
    }
}

extern "C" void kernel_launch(void* const* d_in, const int* in_sizes, int n_in,
                              void* d_out, int out_size, void* d_ws, size_t ws_size,
                              hipStream_t stream) {
    const float* x  = (const float*)d_in[0];
    const float* Wq = (const float*)d_in[1];
    const float* Wk = (const float*)d_in[2];
    const float* Wv = (const float*)d_in[3];
    const float* Wp = (const float*)d_in[4];
    const float* bp = (const float*)d_in[5];
    float* out = (float*)d_out;

    xconv_kernel<<<dim3((B_SZ * T_SZ * E_SZ) / 2048), 256, 0, stream>>>(x);
    wconv_qkv_kernel<<<dim3(3 * H_SZ, E_SZ / 64), 256, 0, stream>>>(Wq, Wk, Wv);
    wconv_p_kernel<<<dim3(E_SZ / 64, E_SZ / 64), 256, 0, stream>>>(Wp);

    qkv_gemm_kernel<<<dim3(512, 24), 256, 0, stream>>>();
    attn_kernel<<<dim3((B_SZ * H_SZ) / 4), 256, 0, stream>>>();
    proj_gemm_kernel<<<dim3(512, 8), 256, 0, stream>>>(out, bp);
}

// Round 2
// 1511.729 us; speedup vs baseline: 2.5309x; 1.1187x over previous
//
#include <hip/hip_runtime.h>
#include <hip/hip_bf16.h>

typedef unsigned short u16;
typedef short short8 __attribute__((ext_vector_type(8)));
typedef short short4v __attribute__((ext_vector_type(4)));
typedef float f32x4 __attribute__((ext_vector_type(4)));

#define B_SZ 2048
#define T_SZ 32
#define E_SZ 1024
#define H_SZ 16
#define HS_SZ 64
// tokens = B*T = 65536; heads total BH = 32768

// Static device intermediates
__device__ __align__(16) u16 g_Wt[3 * E_SZ * E_SZ];            // stacked [Wq^T;Wk^T;Wv^T]: row j=(which,h,d), col e
__device__ __align__(16) u16 g_Wpt[E_SZ * E_SZ];               // (j,e) = Wp^T bf16
__device__ __align__(16) u16 g_xb[(size_t)B_SZ * T_SZ * E_SZ]; // x bf16 [65536][1024]
__device__ __align__(16) u16 g_Q[(size_t)B_SZ * H_SZ * T_SZ * HS_SZ];  // [bh][t][d]
__device__ __align__(16) u16 g_K[(size_t)B_SZ * H_SZ * T_SZ * HS_SZ];  // [bh][t][d]
__device__ __align__(16) u16 g_Vt[(size_t)B_SZ * H_SZ * HS_SZ * T_SZ]; // [bh][d][t]  (transposed!)
__device__ __align__(16) u16 g_O[(size_t)B_SZ * T_SZ * E_SZ];  // attn out bf16 [65536][1024]

__device__ __forceinline__ f32x4 mfma16x16x32(short8 a, short8 b, f32x4 c) {
    return __builtin_amdgcn_mfma_f32_16x16x32_bf16(a, b, c, 0, 0, 0);
}

__device__ __forceinline__ u16 f2bf(float f) {
    __hip_bfloat16 h = __float2bfloat16(f);
    return __builtin_bit_cast(u16, h);
}

// async global->LDS, 16B per lane. lds ptr must be wave-uniform base; HW adds lane*16.
__device__ __forceinline__ void gll16(const void* g, void* l) {
    __builtin_amdgcn_global_load_lds(
        (__attribute__((address_space(1))) void*)g,
        (__attribute__((address_space(3))) void*)l, 16, 0, 0);
}

__device__ __forceinline__ float rmax16(float v) {
    v = fmaxf(v, __shfl_xor(v, 1));
    v = fmaxf(v, __shfl_xor(v, 2));
    v = fmaxf(v, __shfl_xor(v, 4));
    v = fmaxf(v, __shfl_xor(v, 8));
    return v;
}
__device__ __forceinline__ float rsum16(float v) {
    v += __shfl_xor(v, 1);
    v += __shfl_xor(v, 2);
    v += __shfl_xor(v, 4);
    v += __shfl_xor(v, 8);
    return v;
}

// ---------- fp32 -> bf16 convert of x (coalesced float4 loads) ----------
// grid = B*T*E/2048 = 32768 blocks of 256
__global__ __launch_bounds__(256) void xconv_kernel(const float* __restrict__ x) {
    size_t base = (size_t)blockIdx.x * 2048;
    int t = threadIdx.x;
    #pragma unroll
    for (int hh = 0; hh < 2; hh++) {
        size_t i = base + (size_t)hh * 1024 + (size_t)t * 4;
        float4 v = *(const float4*)(x + i);
        short4v o;
        o[0] = (short)f2bf(v.x); o[1] = (short)f2bf(v.y);
        o[2] = (short)f2bf(v.z); o[3] = (short)f2bf(v.w);
        *(short4v*)(g_xb + i) = o;
    }
}

// ---------- Wq/Wk/Wv (H,E,HS) fp32 -> stacked g_Wt rows (which,h,d) over e ----------
// grid=(3*H, E/64), block=256
__global__ __launch_bounds__(256) void wconv_qkv_kernel(
    const float* __restrict__ Wq, const float* __restrict__ Wk,
    const float* __restrict__ Wv)
{
    __shared__ float tile[64][65];
    int which = blockIdx.x >> 4;
    int h = blockIdx.x & 15;
    int rt = blockIdx.y;   // e-tile
    const float* in = (which == 0 ? Wq : which == 1 ? Wk : Wv) + (size_t)h * E_SZ * HS_SZ;
    u16* out = g_Wt + (size_t)which * E_SZ * E_SZ + (size_t)h * HS_SZ * E_SZ;
    int t = threadIdx.x;
    #pragma unroll
    for (int i = 0; i < 16; i++) {
        int idx = t + i * 256;
        int r = idx >> 6, c = idx & 63;
        tile[r][c] = in[(size_t)(rt * 64 + r) * HS_SZ + c];
    }
    __syncthreads();
    #pragma unroll
    for (int i = 0; i < 16; i++) {
        int idx = t + i * 256;
        int r = idx >> 6, c = idx & 63;
        out[(size_t)r * E_SZ + rt * 64 + c] = f2bf(tile[c][r]);
    }
}

// ---------- Wp (E,E) fp32 -> g_Wpt[j][e] = Wp[e][j] bf16 ----------
__global__ __launch_bounds__(256) void wconv_p_kernel(const float* __restrict__ Wp) {
    __shared__ float tile[64][65];
    int rt = blockIdx.x, ct = blockIdx.y;
    int t = threadIdx.x;
    #pragma unroll
    for (int i = 0; i < 16; i++) {
        int idx = t + i * 256;
        int r = idx >> 6, c = idx & 63;
        tile[r][c] = Wp[(size_t)(rt * 64 + r) * E_SZ + ct * 64 + c];
    }
    __syncthreads();
    #pragma unroll
    for (int i = 0; i < 16; i++) {
        int idx = t + i * 256;
        int r = idx >> 6, c = idx & 63;
        g_Wpt[(size_t)(ct * 64 + r) * E_SZ + rt * 64 + c] = f2bf(tile[c][r]);
    }
}

// ---------- QKV GEMM: C[65536][3072] = g_xb @ g_Wt^T ----------
// 128x128 tile, BK=32, 4 waves (2x2), double-buffered LDS, stage-early single-barrier
// K-loop (T3-minimum), bn-fast grid + XCD chunk swizzle for A reuse from L2.
// grid = 12288 blocks (bn fast: 24 per bm), block 256.
__global__ __launch_bounds__(256) void qkv_gemm_kernel() {
    __shared__ u16 smem[16384];   // dbuf: buf c at u16 off c*8192 (A 0..4095, B 4096..8191); epilogue C[128][128]
    int tid = threadIdx.x;
    int wave = tid >> 6, lane = tid & 63;
    int m = lane & 15, quad = lane >> 4;
    int wr = wave >> 1, wc = wave & 1;

    // XCD chunk swizzle: nwg=12288, 1536/XCD. bn fast within chunk.
    int bid = blockIdx.x;
    int swz = (bid & 7) * 1536 + (bid >> 3);
    int bn = swz % 24, bm = swz / 24;

    const u16* Aglob = g_xb + (size_t)bm * 128 * E_SZ;
    const u16* Bglob = g_Wt + (size_t)bn * 128 * E_SZ;

    auto stage = [&](int buf, int k0) {
        #pragma unroll
        for (int i = 0; i < 2; i++) {
            int c = wave * 128 + i * 64 + lane;   // 16B chunk index 0..511
            int row = c >> 2, col = (c & 3) * 8;
            gll16(Aglob + (size_t)row * E_SZ + k0 + col,
                  (char*)smem + buf * 16384 + wave * 2048 + i * 1024);
            gll16(Bglob + (size_t)row * E_SZ + k0 + col,
                  (char*)smem + buf * 16384 + 8192 + wave * 2048 + i * 1024);
        }
    };

    f32x4 acc[4][4] = {};

    stage(0, 0);
    __syncthreads();   // drains vmcnt: buf0 ready

    int cur = 0;
    for (int k0 = 0; k0 < E_SZ; k0 += 32) {
        if (k0 + 32 < E_SZ) stage(cur ^ 1, k0 + 32);   // issue next tile BEFORE compute

        short8 af[4], bf[4];
        #pragma unroll
        for (int mi = 0; mi < 4; mi++)
            af[mi] = *(const short8*)&smem[cur * 8192 + (wr * 64 + mi * 16 + m) * 32 + quad * 8];
        #pragma unroll
        for (int ni = 0; ni < 4; ni++)
            bf[ni] = *(const short8*)&smem[cur * 8192 + 4096 + (wc * 64 + ni * 16 + m) * 32 + quad * 8];
        #pragma unroll
        for (int mi = 0; mi < 4; mi++)
            #pragma unroll
            for (int ni = 0; ni < 4; ni++)
                acc[mi][ni] = mfma16x16x32(af[mi], bf[ni], acc[mi][ni]);

        __syncthreads();   // drains vmcnt (next buf staged) + all reads of cur done
        cur ^= 1;
    }

    // acc -> LDS as bf16 C[128][128]
    #pragma unroll
    for (int mi = 0; mi < 4; mi++)
        #pragma unroll
        for (int ni = 0; ni < 4; ni++) {
            int row = wr * 64 + mi * 16 + quad * 4;
            int col = wc * 64 + ni * 16 + m;
            #pragma unroll
            for (int r = 0; r < 4; r++)
                smem[(row + r) * 128 + col] = f2bf(acc[mi][ni][r]);
        }
    __syncthreads();

    int which = bn >> 3;   // 8 col-tiles per matrix
    if (which < 2) {
        // Q/K flush: [bh][t][d], 16B chunks, 128B-contiguous groups
        u16* dst = (which == 0) ? g_Q : g_K;
        #pragma unroll
        for (int i = 0; i < 8; i++) {
            int c = i * 256 + tid;          // 0..2047
            int row = c >> 4;               // token-local 0..127
            int jloc = (c & 15) * 8;
            int jg = bn * 128 + jloc;
            int h = (jg >> 6) & 15;
            int d0 = jg & 63;
            int rg = bm * 128 + row;
            int b = rg >> 5, t = rg & 31;
            size_t off = (((size_t)(b * 16 + h)) * 32 + t) * 64 + d0;
            *(short8*)(dst + off) = *(const short8*)&smem[row * 128 + jloc];
        }
    } else {
        // V flush transposed: g_Vt[bh][d][t]; stores fully coalesced
        #pragma unroll
        for (int i = 0; i < 8; i++) {
            int c = i * 256 + tid;
            int t8 = (c & 3) * 8;           // t chunk base
            int d  = (c >> 2) & 63;
            int hl = (c >> 8) & 1;
            int bl = c >> 9;                // 0..3
            short8 v;
            #pragma unroll
            for (int k = 0; k < 8; k++)
                v[k] = (short)smem[(bl * 32 + t8 + k) * 128 + hl * 64 + d];
            int h = ((bn * 128 + hl * 64) >> 6) & 15;
            int b = bm * 4 + bl;
            size_t off = (((size_t)(b * 16 + h)) * 64 + d) * 32 + t8;
            *(short8*)(g_Vt + off) = v;
        }
    }
}

// ---------- Attention: one WAVE per (b,h); barrier-light; wave-parallel softmax ----------
// grid = 32768/4 = 8192 blocks of 256
__global__ __launch_bounds__(256) void attn_kernel() {
    __shared__ u16 Ps[4][32][40];   // per-wave P (bf16), padded
    int tid = threadIdx.x;
    int wave = tid >> 6, lane = tid & 63;
    int m = lane & 15, quad = lane >> 4;
    int bh = blockIdx.x * 4 + wave;
    int b = bh >> 4, h = bh & 15;

    const u16* Qb = g_Q  + (size_t)bh * 2048;   // [32][64]
    const u16* Kb = g_K  + (size_t)bh * 2048;   // [32][64]
    const u16* Vb = g_Vt + (size_t)bh * 2048;   // [64][32] (V^T)

    // fragment loads (all independent -> issued up front)
    short8 qf[2][2], kf[2][2], vf[4];
    #pragma unroll
    for (int tr = 0; tr < 2; tr++)
        #pragma unroll
        for (int kc = 0; kc < 2; kc++) {
            qf[tr][kc] = *(const short8*)(Qb + (tr * 16 + m) * 64 + kc * 32 + quad * 8);
            kf[tr][kc] = *(const short8*)(Kb + (tr * 16 + m) * 64 + kc * 32 + quad * 8);
        }
    #pragma unroll
    for (int nc = 0; nc < 4; nc++)
        vf[nc] = *(const short8*)(Vb + (nc * 16 + m) * 32 + quad * 8);

    // S = Q K^T (32x32). Tile (0,1) fully causal-masked -> 3 tiles, 6 MFMAs.
    f32x4 s00 = {}, s10 = {}, s11 = {};
    #pragma unroll
    for (int kc = 0; kc < 2; kc++) {
        s00 = mfma16x16x32(qf[0][kc], kf[0][kc], s00);
        s10 = mfma16x16x32(qf[1][kc], kf[0][kc], s10);
        s11 = mfma16x16x32(qf[1][kc], kf[1][kc], s11);
    }

    // wave-parallel causal softmax. Row t lives in the 16 lanes of one quad group.
    #pragma unroll
    for (int r = 0; r < 4; r++) {
        int t0 = quad * 4 + r;
        bool ok = (m <= t0);               // mask for tiles (0,0) and (1,1)
        float x00 = ok ? s00[r] * 0.125f : -1e30f;
        float x10 = s10[r] * 0.125f;       // tile (1,0): always valid
        float x11 = ok ? s11[r] * 0.125f : -1e30f;
        float mx0 = rmax16(x00);
        float mx1 = rmax16(fmaxf(x10, x11));
        float e00 = ok ? __expf(x00 - mx0) : 0.f;
        float e10 = __expf(x10 - mx1);
        float e11 = ok ? __expf(x11 - mx1) : 0.f;
        float inv0 = 1.f / rsum16(e00);
        float inv1 = 1.f / rsum16(e10 + e11);
        Ps[wave][t0][m]           = f2bf(e00 * inv0);
        Ps[wave][t0][16 + m]      = 0;          // masked tile (0,1)
        Ps[wave][16 + t0][m]      = f2bf(e10 * inv1);
        Ps[wave][16 + t0][16 + m] = f2bf(e11 * inv1);
    }
    __syncthreads();

    // O = P (32x32) @ V (32x64): K=32 -> 1 MFMA per 16x16 tile, 8 total.
    short8 pa[2];
    pa[0] = *(const short8*)&Ps[wave][m][quad * 8];
    pa[1] = *(const short8*)&Ps[wave][16 + m][quad * 8];
    f32x4 o[2][4];
    #pragma unroll
    for (int tr = 0; tr < 2; tr++)
        #pragma unroll
        for (int nc = 0; nc < 4; nc++)
            o[tr][nc] = mfma16x16x32(pa[tr], vf[nc], f32x4{});

    u16* ob = g_O + ((size_t)b * 32) * E_SZ + h * 64;
    #pragma unroll
    for (int tr = 0; tr < 2; tr++)
        #pragma unroll
        for (int nc = 0; nc < 4; nc++)
            #pragma unroll
            for (int r = 0; r < 4; r++) {
                int t = tr * 16 + quad * 4 + r;
                ob[(size_t)t * E_SZ + nc * 16 + m] = f2bf(o[tr][nc][r]);
            }
}

// ---------- proj GEMM: out[65536][1024] fp32 = g_O @ Wp + bp ----------
// same dbuf stage-early structure; bn-fast grid + XCD chunk swizzle.
// grid = 4096 blocks (bn fast: 8 per bm), block 256.
__global__ __launch_bounds__(256) void proj_gemm_kernel(
    float* __restrict__ out, const float* __restrict__ bp)
{
    __shared__ u16 smem[16384];   // dbuf: buf c at u16 off c*8192
    int tid = threadIdx.x;
    int wave = tid >> 6, lane = tid & 63;
    int m = lane & 15, quad = lane >> 4;
    int wr = wave >> 1, wc = wave & 1;

    // XCD chunk swizzle: nwg=4096, 512/XCD. bn fast within chunk.
    int bid = blockIdx.x;
    int swz = (bid & 7) * 512 + (bid >> 3);
    int bn = swz & 7, bm = swz >> 3;

    const u16* Aglob = g_O + (size_t)bm * 128 * E_SZ;
    const u16* Bglob = g_Wpt + (size_t)bn * 128 * E_SZ;

    auto stage = [&](int buf, int k0) {
        #pragma unroll
        for (int i = 0; i < 2; i++) {
            int c = wave * 128 + i * 64 + lane;
            int row = c >> 2, col = (c & 3) * 8;
            gll16(Aglob + (size_t)row * E_SZ + k0 + col,
                  (char*)smem + buf * 16384 + wave * 2048 + i * 1024);
            gll16(Bglob + (size_t)row * E_SZ + k0 + col,
                  (char*)smem + buf * 16384 + 8192 + wave * 2048 + i * 1024);
        }
    };

    f32x4 acc[4][4] = {};

    stage(0, 0);
    __syncthreads();

    int cur = 0;
    for (int k0 = 0; k0 < E_SZ; k0 += 32) {
        if (k0 + 32 < E_SZ) stage(cur ^ 1, k0 + 32);

        short8 af[4], bf[4];
        #pragma unroll
        for (int mi = 0; mi < 4; mi++)
            af[mi] = *(const short8*)&smem[cur * 8192 + (wr * 64 + mi * 16 + m) * 32 + quad * 8];
        #pragma unroll
        for (int ni = 0; ni < 4; ni++)
            bf[ni] = *(const short8*)&smem[cur * 8192 + 4096 + (wc * 64 + ni * 16 + m) * 32 + quad * 8];
        #pragma unroll
        for (int mi = 0; mi < 4; mi++)
            #pragma unroll
            for (int ni = 0; ni < 4; ni++)
                acc[mi][ni] = mfma16x16x32(af[mi], bf[ni], acc[mi][ni]);

        __syncthreads();
        cur ^= 1;
    }

    // direct fp32 epilogue + bias
    #pragma unroll
    for (int ni = 0; ni < 4; ni++) {
        int j = bn * 128 + wc * 64 + ni * 16 + m;
        float bias = bp[j];
        #pragma unroll
        for (int mi = 0; mi < 4; mi++) {
            size_t rg = (size_t)bm * 128 + wr * 64 + mi * 16 + quad * 4;
            #pragma unroll
            for (int r = 0; r < 4; r++)
                out[(rg + r) * E_SZ + j] = acc[mi][ni][r] + bias;
        }
    }
}

extern "C" void kernel_launch(void* const* d_in, const int* in_sizes, int n_in,
                              void* d_out, int out_size, void* d_ws, size_t ws_size,
                              hipStream_t stream) {
    const float* x  = (const float*)d_in[0];
    const float* Wq = (const float*)d_in[1];
    const float* Wk = (const float*)d_in[2];
    const float* Wv = (const float*)d_in[3];
    const float* Wp = (const float*)d_in[4];
    const float* bp = (const float*)d_in[5];
    float* out = (float*)d_out;

    xconv_kernel<<<dim3((B_SZ * T_SZ * E_SZ) / 2048), 256, 0, stream>>>(x);
    wconv_qkv_kernel<<<dim3(3 * H_SZ, E_SZ / 64), 256, 0, stream>>>(Wq, Wk, Wv);
    wconv_p_kernel<<<dim3(E_SZ / 64, E_SZ / 64), 256, 0, stream>>>(Wp);

    qkv_gemm_kernel<<<dim3(12288), 256, 0, stream>>>();
    attn_kernel<<<dim3((B_SZ * H_SZ) / 4), 256, 0, stream>>>();
    proj_gemm_kernel<<<dim3(4096), 256, 0, stream>>>(out, bp);
}

// Round 3
// 1425.283 us; speedup vs baseline: 2.6844x; 1.0607x over previous
//
#include <hip/hip_runtime.h>
#include <hip/hip_bf16.h>

typedef unsigned short u16;
typedef short short8 __attribute__((ext_vector_type(8)));
typedef short short4v __attribute__((ext_vector_type(4)));
typedef float f32x4 __attribute__((ext_vector_type(4)));

#define B_SZ 2048
#define T_SZ 32
#define E_SZ 1024
#define H_SZ 16
#define HS_SZ 64
// tokens = B*T = 65536; heads total BH = 32768

// Static device intermediates
__device__ __align__(16) u16 g_Wt[3 * E_SZ * E_SZ];            // stacked [Wq^T;Wk^T;Wv^T]: row j=(which,h,d), col e
__device__ __align__(16) u16 g_Wpt[E_SZ * E_SZ];               // (j,e) = Wp^T bf16
__device__ __align__(16) u16 g_xb[(size_t)B_SZ * T_SZ * E_SZ]; // x bf16 [65536][1024]
__device__ __align__(16) u16 g_Q[(size_t)B_SZ * H_SZ * T_SZ * HS_SZ];  // [bh][t][d]
__device__ __align__(16) u16 g_K[(size_t)B_SZ * H_SZ * T_SZ * HS_SZ];  // [bh][t][d]
__device__ __align__(16) u16 g_Vt[(size_t)B_SZ * H_SZ * HS_SZ * T_SZ]; // [bh][d][t]  (transposed!)
__device__ __align__(16) u16 g_O[(size_t)B_SZ * T_SZ * E_SZ];  // attn out bf16 [65536][1024]

__device__ __forceinline__ f32x4 mfma16x16x32(short8 a, short8 b, f32x4 c) {
    return __builtin_amdgcn_mfma_f32_16x16x32_bf16(a, b, c, 0, 0, 0);
}

__device__ __forceinline__ u16 f2bf(float f) {
    __hip_bfloat16 h = __float2bfloat16(f);
    return __builtin_bit_cast(u16, h);
}

// async global->LDS, 16B per lane. lds ptr must be wave-uniform base; HW adds lane*16.
__device__ __forceinline__ void gll16(const void* g, void* l) {
    __builtin_amdgcn_global_load_lds(
        (__attribute__((address_space(1))) void*)g,
        (__attribute__((address_space(3))) void*)l, 16, 0, 0);
}

__device__ __forceinline__ float rmax16(float v) {
    v = fmaxf(v, __shfl_xor(v, 1));
    v = fmaxf(v, __shfl_xor(v, 2));
    v = fmaxf(v, __shfl_xor(v, 4));
    v = fmaxf(v, __shfl_xor(v, 8));
    return v;
}
__device__ __forceinline__ float rsum16(float v) {
    v += __shfl_xor(v, 1);
    v += __shfl_xor(v, 2);
    v += __shfl_xor(v, 4);
    v += __shfl_xor(v, 8);
    return v;
}

// ---------- fp32 -> bf16 convert of x (coalesced float4 loads) ----------
__global__ __launch_bounds__(256) void xconv_kernel(const float* __restrict__ x) {
    size_t base = (size_t)blockIdx.x * 2048;
    int t = threadIdx.x;
    #pragma unroll
    for (int hh = 0; hh < 2; hh++) {
        size_t i = base + (size_t)hh * 1024 + (size_t)t * 4;
        float4 v = *(const float4*)(x + i);
        short4v o;
        o[0] = (short)f2bf(v.x); o[1] = (short)f2bf(v.y);
        o[2] = (short)f2bf(v.z); o[3] = (short)f2bf(v.w);
        *(short4v*)(g_xb + i) = o;
    }
}

// ---------- Wq/Wk/Wv (H,E,HS) fp32 -> stacked g_Wt rows (which,h,d) over e ----------
__global__ __launch_bounds__(256) void wconv_qkv_kernel(
    const float* __restrict__ Wq, const float* __restrict__ Wk,
    const float* __restrict__ Wv)
{
    __shared__ float tile[64][65];
    int which = blockIdx.x >> 4;
    int h = blockIdx.x & 15;
    int rt = blockIdx.y;   // e-tile
    const float* in = (which == 0 ? Wq : which == 1 ? Wk : Wv) + (size_t)h * E_SZ * HS_SZ;
    u16* out = g_Wt + (size_t)which * E_SZ * E_SZ + (size_t)h * HS_SZ * E_SZ;
    int t = threadIdx.x;
    #pragma unroll
    for (int i = 0; i < 16; i++) {
        int idx = t + i * 256;
        int r = idx >> 6, c = idx & 63;
        tile[r][c] = in[(size_t)(rt * 64 + r) * HS_SZ + c];
    }
    __syncthreads();
    #pragma unroll
    for (int i = 0; i < 16; i++) {
        int idx = t + i * 256;
        int r = idx >> 6, c = idx & 63;
        out[(size_t)r * E_SZ + rt * 64 + c] = f2bf(tile[c][r]);
    }
}

// ---------- Wp (E,E) fp32 -> g_Wpt[j][e] = Wp[e][j] bf16 ----------
__global__ __launch_bounds__(256) void wconv_p_kernel(const float* __restrict__ Wp) {
    __shared__ float tile[64][65];
    int rt = blockIdx.x, ct = blockIdx.y;
    int t = threadIdx.x;
    #pragma unroll
    for (int i = 0; i < 16; i++) {
        int idx = t + i * 256;
        int r = idx >> 6, c = idx & 63;
        tile[r][c] = Wp[(size_t)(rt * 64 + r) * E_SZ + ct * 64 + c];
    }
    __syncthreads();
    #pragma unroll
    for (int i = 0; i < 16; i++) {
        int idx = t + i * 256;
        int r = idx >> 6, c = idx & 63;
        g_Wpt[(size_t)(ct * 64 + r) * E_SZ + rt * 64 + c] = f2bf(tile[c][r]);
    }
}

// ---------- QKV GEMM: C[65536][3072] = g_xb @ g_Wt^T ----------
// 128x128 tile, BK=32, 4 waves (2x2). 3-slot LDS pipeline with counted vmcnt +
// raw s_barrier (never drains in main loop). LDS frag reads bank-deswizzled via
// inverse-swizzled global source (rule 21). 2D (4bm x 6bn) chunk-per-XCD swizzle
// keeps L2 working set ~2.5 MB. grid = 12288, block 256. LDS 48 KB -> 3 blk/CU.
__global__ __launch_bounds__(256) void qkv_gemm_kernel() {
    __shared__ u16 smem[24576];   // 3 slots x 16 KB (A 8KB + B 8KB); epilogue reuses [0..16384) as C
    int tid = threadIdx.x;
    int wave = tid >> 6, lane = tid & 63;
    int m = lane & 15, quad = lane >> 4;
    int wr = wave >> 1, wc = wave & 1;

    // 2D chunk swizzle: XCD x owns bm in [x*64,(x+1)*64). Within XCD: bn-band (6 wide)
    // outer, then 16 chunks of 4bm x 6bn. L2 set: ~4 A-tiles (1MB) + 6 B-tiles (1.5MB).
    int bid = blockIdx.x;
    int xcd = bid & 7, l = bid >> 3;      // l in [0,1536)
    int bnc = l / 384; int r1 = l - bnc * 384;
    int bmc = r1 / 24;  int r2 = r1 - bmc * 24;
    int ibm = r2 / 6;   int ibn = r2 - ibm * 6;
    int bm = xcd * 64 + bmc * 4 + ibm;    // [0,512)
    int bn = bnc * 6 + ibn;               // [0,24)

    const u16* Aglob = g_xb + (size_t)bm * 128 * E_SZ;
    const u16* Bglob = g_Wt + (size_t)bn * 128 * E_SZ;

    // Staging address precompute. Linear LDS dest slot o = wave*2048 + i*1024 + lane*16 B.
    // row = o>>6, storage chunk cs = lane&3. Inverse-swizzle source: lc = cs ^ (row&3).
    int srow0 = wave * 32 + (lane >> 2);                    // i=0 rows; i=1 adds 16
    int lc8 = ((lane & 3) ^ ((lane >> 2) & 3)) * 8;
    const u16* gA0 = Aglob + (size_t)srow0 * E_SZ + lc8;
    const u16* gA1 = gA0 + (size_t)16 * E_SZ;
    const u16* gB0 = Bglob + (size_t)srow0 * E_SZ + lc8;
    const u16* gB1 = gB0 + (size_t)16 * E_SZ;

    auto stage = [&](int s) {
        int k0 = s * 32;
        char* base = (char*)smem + (s % 3) * 16384 + wave * 2048;
        gll16(gA0 + k0, base);
        gll16(gA1 + k0, base + 1024);
        gll16(gB0 + k0, base + 8192);
        gll16(gB1 + k0, base + 8192 + 1024);
    };

    // Swizzled frag-read chunk: logical chunk=quad, row&3 = m&3 -> storage chunk quad^(m&3).
    int cix = (quad ^ (m & 3)) * 8;

    f32x4 acc[4][4] = {};

    stage(0); stage(1);   // 8 loads in flight

    for (int s = 0; s < 32; s++) {
        // Drain exactly stage(s): 4 loads/thread/stage, stage(s+1) stays in flight.
        if (s == 31) asm volatile("s_waitcnt vmcnt(0)" ::: "memory");
        else         asm volatile("s_waitcnt vmcnt(4)" ::: "memory");
        asm volatile("s_barrier" ::: "memory");   // raw: no implicit vmcnt(0) drain
        if (s < 30) stage(s + 2);                 // writes slot (s+2)%3 == (s-1)%3: safe past barrier

        int su = (s % 3) * 8192;                  // u16 units
        short8 af[4], bf[4];
        #pragma unroll
        for (int mi = 0; mi < 4; mi++)
            af[mi] = *(const short8*)&smem[su + (wr * 64 + mi * 16 + m) * 32 + cix];
        #pragma unroll
        for (int ni = 0; ni < 4; ni++)
            bf[ni] = *(const short8*)&smem[su + 4096 + (wc * 64 + ni * 16 + m) * 32 + cix];
        #pragma unroll
        for (int mi = 0; mi < 4; mi++)
            #pragma unroll
            for (int ni = 0; ni < 4; ni++)
                acc[mi][ni] = mfma16x16x32(af[mi], bf[ni], acc[mi][ni]);
    }
    __syncthreads();   // full drain before slot memory is reused as C

    // acc -> LDS as bf16 C[128][128]
    #pragma unroll
    for (int mi = 0; mi < 4; mi++)
        #pragma unroll
        for (int ni = 0; ni < 4; ni++) {
            int row = wr * 64 + mi * 16 + quad * 4;
            int col = wc * 64 + ni * 16 + m;
            #pragma unroll
            for (int r = 0; r < 4; r++)
                smem[(row + r) * 128 + col] = f2bf(acc[mi][ni][r]);
        }
    __syncthreads();

    int which = bn >> 3;   // 8 col-tiles per matrix
    if (which < 2) {
        // Q/K flush: [bh][t][d], 16B chunks, 128B-contiguous groups
        u16* dst = (which == 0) ? g_Q : g_K;
        #pragma unroll
        for (int i = 0; i < 8; i++) {
            int c = i * 256 + tid;          // 0..2047
            int row = c >> 4;               // token-local 0..127
            int jloc = (c & 15) * 8;
            int jg = bn * 128 + jloc;
            int h = (jg >> 6) & 15;
            int d0 = jg & 63;
            int rg = bm * 128 + row;
            int b = rg >> 5, t = rg & 31;
            size_t off = (((size_t)(b * 16 + h)) * 32 + t) * 64 + d0;
            *(short8*)(dst + off) = *(const short8*)&smem[row * 128 + jloc];
        }
    } else {
        // V flush transposed: g_Vt[bh][d][t]; stores fully coalesced
        #pragma unroll
        for (int i = 0; i < 8; i++) {
            int c = i * 256 + tid;
            int t8 = (c & 3) * 8;           // t chunk base
            int d  = (c >> 2) & 63;
            int hl = (c >> 8) & 1;
            int bl = c >> 9;                // 0..3
            short8 v;
            #pragma unroll
            for (int k = 0; k < 8; k++)
                v[k] = (short)smem[(bl * 32 + t8 + k) * 128 + hl * 64 + d];
            int h = ((bn * 128 + hl * 64) >> 6) & 15;
            int b = bm * 4 + bl;
            size_t off = (((size_t)(b * 16 + h)) * 64 + d) * 32 + t8;
            *(short8*)(g_Vt + off) = v;
        }
    }
}

// ---------- Attention: one WAVE per (b,h); barrier-light; wave-parallel softmax ----------
// grid = 32768/4 = 8192 blocks of 256
__global__ __launch_bounds__(256) void attn_kernel() {
    __shared__ u16 Ps[4][32][40];   // per-wave P (bf16), padded
    int tid = threadIdx.x;
    int wave = tid >> 6, lane = tid & 63;
    int m = lane & 15, quad = lane >> 4;
    int bh = blockIdx.x * 4 + wave;
    int b = bh >> 4, h = bh & 15;

    const u16* Qb = g_Q  + (size_t)bh * 2048;   // [32][64]
    const u16* Kb = g_K  + (size_t)bh * 2048;   // [32][64]
    const u16* Vb = g_Vt + (size_t)bh * 2048;   // [64][32] (V^T)

    short8 qf[2][2], kf[2][2], vf[4];
    #pragma unroll
    for (int tr = 0; tr < 2; tr++)
        #pragma unroll
        for (int kc = 0; kc < 2; kc++) {
            qf[tr][kc] = *(const short8*)(Qb + (tr * 16 + m) * 64 + kc * 32 + quad * 8);
            kf[tr][kc] = *(const short8*)(Kb + (tr * 16 + m) * 64 + kc * 32 + quad * 8);
        }
    #pragma unroll
    for (int nc = 0; nc < 4; nc++)
        vf[nc] = *(const short8*)(Vb + (nc * 16 + m) * 32 + quad * 8);

    // S = Q K^T (32x32). Tile (0,1) fully causal-masked -> 3 tiles, 6 MFMAs.
    f32x4 s00 = {}, s10 = {}, s11 = {};
    #pragma unroll
    for (int kc = 0; kc < 2; kc++) {
        s00 = mfma16x16x32(qf[0][kc], kf[0][kc], s00);
        s10 = mfma16x16x32(qf[1][kc], kf[0][kc], s10);
        s11 = mfma16x16x32(qf[1][kc], kf[1][kc], s11);
    }

    // wave-parallel causal softmax. Row t lives in the 16 lanes of one quad group.
    #pragma unroll
    for (int r = 0; r < 4; r++) {
        int t0 = quad * 4 + r;
        bool ok = (m <= t0);               // mask for tiles (0,0) and (1,1)
        float x00 = ok ? s00[r] * 0.125f : -1e30f;
        float x10 = s10[r] * 0.125f;       // tile (1,0): always valid
        float x11 = ok ? s11[r] * 0.125f : -1e30f;
        float mx0 = rmax16(x00);
        float mx1 = rmax16(fmaxf(x10, x11));
        float e00 = ok ? __expf(x00 - mx0) : 0.f;
        float e10 = __expf(x10 - mx1);
        float e11 = ok ? __expf(x11 - mx1) : 0.f;
        float inv0 = 1.f / rsum16(e00);
        float inv1 = 1.f / rsum16(e10 + e11);
        Ps[wave][t0][m]           = f2bf(e00 * inv0);
        Ps[wave][t0][16 + m]      = 0;          // masked tile (0,1)
        Ps[wave][16 + t0][m]      = f2bf(e10 * inv1);
        Ps[wave][16 + t0][16 + m] = f2bf(e11 * inv1);
    }
    __syncthreads();

    // O = P (32x32) @ V (32x64): K=32 -> 1 MFMA per 16x16 tile, 8 total.
    short8 pa[2];
    pa[0] = *(const short8*)&Ps[wave][m][quad * 8];
    pa[1] = *(const short8*)&Ps[wave][16 + m][quad * 8];
    f32x4 o[2][4];
    #pragma unroll
    for (int tr = 0; tr < 2; tr++)
        #pragma unroll
        for (int nc = 0; nc < 4; nc++)
            o[tr][nc] = mfma16x16x32(pa[tr], vf[nc], f32x4{});

    u16* ob = g_O + ((size_t)b * 32) * E_SZ + h * 64;
    #pragma unroll
    for (int tr = 0; tr < 2; tr++)
        #pragma unroll
        for (int nc = 0; nc < 4; nc++)
            #pragma unroll
            for (int r = 0; r < 4; r++) {
                int t = tr * 16 + quad * 4 + r;
                ob[(size_t)t * E_SZ + nc * 16 + m] = f2bf(o[tr][nc][r]);
            }
}

// ---------- proj GEMM: out[65536][1024] fp32 = g_O @ Wp + bp ----------
// Same 3-slot counted-vmcnt pipeline + deswizzle. B total = 2 MB (L2-resident).
// grid = 4096, block 256. LDS 48 KB -> 3 blk/CU.
__global__ __launch_bounds__(256) void proj_gemm_kernel(
    float* __restrict__ out, const float* __restrict__ bp)
{
    __shared__ u16 smem[24576];
    int tid = threadIdx.x;
    int wave = tid >> 6, lane = tid & 63;
    int m = lane & 15, quad = lane >> 4;
    int wr = wave >> 1, wc = wave & 1;

    // per-XCD: 16 chunks of (4bm x 8bn), bn fast (B band = full 2 MB, stays L2-hot)
    int bid = blockIdx.x;
    int xcd = bid & 7, l = bid >> 3;      // [0,512)
    int bmc = l >> 5;  int r2 = l & 31;
    int ibm = r2 >> 3; int bn = r2 & 7;
    int bm = xcd * 64 + bmc * 4 + ibm;

    const u16* Aglob = g_O + (size_t)bm * 128 * E_SZ;
    const u16* Bglob = g_Wpt + (size_t)bn * 128 * E_SZ;

    int srow0 = wave * 32 + (lane >> 2);
    int lc8 = ((lane & 3) ^ ((lane >> 2) & 3)) * 8;
    const u16* gA0 = Aglob + (size_t)srow0 * E_SZ + lc8;
    const u16* gA1 = gA0 + (size_t)16 * E_SZ;
    const u16* gB0 = Bglob + (size_t)srow0 * E_SZ + lc8;
    const u16* gB1 = gB0 + (size_t)16 * E_SZ;

    auto stage = [&](int s) {
        int k0 = s * 32;
        char* base = (char*)smem + (s % 3) * 16384 + wave * 2048;
        gll16(gA0 + k0, base);
        gll16(gA1 + k0, base + 1024);
        gll16(gB0 + k0, base + 8192);
        gll16(gB1 + k0, base + 8192 + 1024);
    };

    int cix = (quad ^ (m & 3)) * 8;

    f32x4 acc[4][4] = {};

    stage(0); stage(1);

    for (int s = 0; s < 32; s++) {
        if (s == 31) asm volatile("s_waitcnt vmcnt(0)" ::: "memory");
        else         asm volatile("s_waitcnt vmcnt(4)" ::: "memory");
        asm volatile("s_barrier" ::: "memory");
        if (s < 30) stage(s + 2);

        int su = (s % 3) * 8192;
        short8 af[4], bf[4];
        #pragma unroll
        for (int mi = 0; mi < 4; mi++)
            af[mi] = *(const short8*)&smem[su + (wr * 64 + mi * 16 + m) * 32 + cix];
        #pragma unroll
        for (int ni = 0; ni < 4; ni++)
            bf[ni] = *(const short8*)&smem[su + 4096 + (wc * 64 + ni * 16 + m) * 32 + cix];
        #pragma unroll
        for (int mi = 0; mi < 4; mi++)
            #pragma unroll
            for (int ni = 0; ni < 4; ni++)
                acc[mi][ni] = mfma16x16x32(af[mi], bf[ni], acc[mi][ni]);
    }

    // direct fp32 epilogue + bias
    #pragma unroll
    for (int ni = 0; ni < 4; ni++) {
        int j = bn * 128 + wc * 64 + ni * 16 + m;
        float bias = bp[j];
        #pragma unroll
        for (int mi = 0; mi < 4; mi++) {
            size_t rg = (size_t)bm * 128 + wr * 64 + mi * 16 + quad * 4;
            #pragma unroll
            for (int r = 0; r < 4; r++)
                out[(rg + r) * E_SZ + j] = acc[mi][ni][r] + bias;
        }
    }
}

extern "C" void kernel_launch(void* const* d_in, const int* in_sizes, int n_in,
                              void* d_out, int out_size, void* d_ws, size_t ws_size,
                              hipStream_t stream) {
    const float* x  = (const float*)d_in[0];
    const float* Wq = (const float*)d_in[1];
    const float* Wk = (const float*)d_in[2];
    const float* Wv = (const float*)d_in[3];
    const float* Wp = (const float*)d_in[4];
    const float* bp = (const float*)d_in[5];
    float* out = (float*)d_out;

    xconv_kernel<<<dim3((B_SZ * T_SZ * E_SZ) / 2048), 256, 0, stream>>>(x);
    wconv_qkv_kernel<<<dim3(3 * H_SZ, E_SZ / 64), 256, 0, stream>>>(Wq, Wk, Wv);
    wconv_p_kernel<<<dim3(E_SZ / 64, E_SZ / 64), 256, 0, stream>>>(Wp);

    qkv_gemm_kernel<<<dim3(12288), 256, 0, stream>>>();
    attn_kernel<<<dim3((B_SZ * H_SZ) / 4), 256, 0, stream>>>();
    proj_gemm_kernel<<<dim3(4096), 256, 0, stream>>>(out, bp);
}